// Round 3
// baseline (438.800 us; speedup 1.0000x reference)
//
#include <hip/hip_runtime.h>

static constexpr int B_    = 64;
static constexpr int N_    = 2048;
static constexpr int DI_   = 8;
static constexpr int O_    = 32;
static constexpr int P_    = 16;
static constexpr int OP_   = O_ * P_;      // 512
static constexpr int NBLK_ = 512;
static constexpr int CHUNK_ = N_ / NBLK_;  // 4

__device__ __forceinline__ float dot8(const float* __restrict__ wp,
                                      const float4& xa, const float4& xb) {
  float pr = wp[0] * xa.x;
  pr = __builtin_fmaf(wp[1], xa.y, pr);
  pr = __builtin_fmaf(wp[2], xa.z, pr);
  pr = __builtin_fmaf(wp[3], xa.w, pr);
  pr = __builtin_fmaf(wp[4], xb.x, pr);
  pr = __builtin_fmaf(wp[5], xb.y, pr);
  pr = __builtin_fmaf(wp[6], xb.z, pr);
  pr = __builtin_fmaf(wp[7], xb.w, pr);
  return pr;
}

// MODE 0: iter0 (uniform rw; 1/32 folded into v_kernel scale). Phase B only.
// MODE 1: phase A (logits vs v_in) + softmax + phase B.
// MODE 2: MODE1 + write normalized rw to rw_out (v_in = v0+v1 by linearity).
// s accumulated via device-scope atomicAdd into a pre-zeroed 131 KB buffer.
template <int MODE>
__global__ __launch_bounds__(1024, 8)
void fused_pass(const float* __restrict__ x, const float* __restrict__ W,
                const float* __restrict__ v_in, float* __restrict__ s_out,
                float* __restrict__ rw_out) {
  __shared__ float x_lds[32 * 65];            // [rem=(nn*8+i)][b], pad 65 (8.3 KB)
  __shared__ float a_lds[CHUNK_ * O_ * B_];   // 32 KB: [nn][o][b] logits -> rw
  const int tid  = threadIdx.x;
  const int lane = tid & 63;                  // lane == batch b
  const int wave = tid >> 6;                  // 0..15
  const int n0   = blockIdx.x * CHUNK_;

  // stage x[b][n0..n0+3][i] -> LDS (128B contiguous per b, conflict-free write)
  #pragma unroll
  for (int k = 0; k < 2; ++k) {
    int d = k * 1024 + tid;
    int b = d >> 5, rem = d & 31;
    x_lds[rem * 65 + b] = x[b * (N_ * DI_) + n0 * DI_ + rem];
  }
  __syncthreads();

  if (MODE != 0) {
    // ---- phase A: a[nn][o][b] = <preds(b,n,o,:), v(b,o,:)> ----
    #pragma unroll 1
    for (int oo = 0; oo < 2; ++oo) {
      const int o   = wave * 2 + oo;
      const int o_u = __builtin_amdgcn_readfirstlane(o);
      const float4* vp = (const float4*)(v_in + (size_t)lane * OP_ + o * P_);
      float4 v0 = vp[0], v1 = vp[1], v2 = vp[2], v3 = vp[3];
      #pragma unroll 2
      for (int nn = 0; nn < CHUNK_; ++nn) {
        const float* wp = W + (size_t)((n0 + nn) * O_ + o_u) * (P_ * DI_);
        const float* xp = &x_lds[nn * 8 * 65 + lane];
        float4 xa, xb;
        xa.x = xp[0];   xa.y = xp[65];  xa.z = xp[130]; xa.w = xp[195];
        xb.x = xp[260]; xb.y = xp[325]; xb.z = xp[390]; xb.w = xp[455];
        float a;
        a = dot8(wp +   0, xa, xb) * v0.x;
        a = __builtin_fmaf(dot8(wp +   8, xa, xb), v0.y, a);
        a = __builtin_fmaf(dot8(wp +  16, xa, xb), v0.z, a);
        a = __builtin_fmaf(dot8(wp +  24, xa, xb), v0.w, a);
        a = __builtin_fmaf(dot8(wp +  32, xa, xb), v1.x, a);
        a = __builtin_fmaf(dot8(wp +  40, xa, xb), v1.y, a);
        a = __builtin_fmaf(dot8(wp +  48, xa, xb), v1.z, a);
        a = __builtin_fmaf(dot8(wp +  56, xa, xb), v1.w, a);
        a = __builtin_fmaf(dot8(wp +  64, xa, xb), v2.x, a);
        a = __builtin_fmaf(dot8(wp +  72, xa, xb), v2.y, a);
        a = __builtin_fmaf(dot8(wp +  80, xa, xb), v2.z, a);
        a = __builtin_fmaf(dot8(wp +  88, xa, xb), v2.w, a);
        a = __builtin_fmaf(dot8(wp +  96, xa, xb), v3.x, a);
        a = __builtin_fmaf(dot8(wp + 104, xa, xb), v3.y, a);
        a = __builtin_fmaf(dot8(wp + 112, xa, xb), v3.z, a);
        a = __builtin_fmaf(dot8(wp + 120, xa, xb), v3.w, a);
        a_lds[(nn * O_ + o) * B_ + lane] = a;
      }
    }
    __syncthreads();

    // ---- softmax over o (in-lane; wave nn handles its row) ----
    if (wave < CHUNK_) {
      const int nn = wave;
      float* ap = &a_lds[nn * O_ * B_ + lane];
      float m = -3.0e38f;
      #pragma unroll
      for (int o = 0; o < O_; ++o) m = fmaxf(m, ap[o * B_]);
      float Z = 0.0f;
      #pragma unroll
      for (int o = 0; o < O_; ++o) Z += __expf(ap[o * B_] - m);
      float rZ = 1.0f / Z;
      if (MODE == 2) {
        float* rp = rw_out + ((size_t)lane * N_ + (n0 + nn)) * O_;
        #pragma unroll
        for (int o4 = 0; o4 < 8; ++o4) {
          float4 t;
          t.x = __expf(ap[(o4 * 4 + 0) * B_] - m) * rZ;
          t.y = __expf(ap[(o4 * 4 + 1) * B_] - m) * rZ;
          t.z = __expf(ap[(o4 * 4 + 2) * B_] - m) * rZ;
          t.w = __expf(ap[(o4 * 4 + 3) * B_] - m) * rZ;
          ap[(o4 * 4 + 0) * B_] = t.x;
          ap[(o4 * 4 + 1) * B_] = t.y;
          ap[(o4 * 4 + 2) * B_] = t.z;
          ap[(o4 * 4 + 3) * B_] = t.w;
          ((float4*)rp)[o4] = t;
        }
      } else {
        #pragma unroll
        for (int o = 0; o < O_; ++o) ap[o * B_] = __expf(ap[o * B_] - m) * rZ;
      }
    }
    __syncthreads();
  }

  // ---- phase B: s[b,o,p] += rw * preds (recompute preds), atomic to global ----
  #pragma unroll 1
  for (int oo = 0; oo < 2; ++oo) {
    const int o   = wave * 2 + oo;
    const int o_u = __builtin_amdgcn_readfirstlane(o);
    float4 s0 = {0,0,0,0}, s1 = {0,0,0,0}, s2 = {0,0,0,0}, s3 = {0,0,0,0};
    #pragma unroll 2
    for (int nn = 0; nn < CHUNK_; ++nn) {
      const float* wp = W + (size_t)((n0 + nn) * O_ + o_u) * (P_ * DI_);
      const float* xp = &x_lds[nn * 8 * 65 + lane];
      float4 xa, xb;
      xa.x = xp[0];   xa.y = xp[65];  xa.z = xp[130]; xa.w = xp[195];
      xb.x = xp[260]; xb.y = xp[325]; xb.z = xp[390]; xb.w = xp[455];
      const float sc = (MODE == 0) ? 1.0f : a_lds[(nn * O_ + o) * B_ + lane];
      s0.x = __builtin_fmaf(sc, dot8(wp +   0, xa, xb), s0.x);
      s0.y = __builtin_fmaf(sc, dot8(wp +   8, xa, xb), s0.y);
      s0.z = __builtin_fmaf(sc, dot8(wp +  16, xa, xb), s0.z);
      s0.w = __builtin_fmaf(sc, dot8(wp +  24, xa, xb), s0.w);
      s1.x = __builtin_fmaf(sc, dot8(wp +  32, xa, xb), s1.x);
      s1.y = __builtin_fmaf(sc, dot8(wp +  40, xa, xb), s1.y);
      s1.z = __builtin_fmaf(sc, dot8(wp +  48, xa, xb), s1.z);
      s1.w = __builtin_fmaf(sc, dot8(wp +  56, xa, xb), s1.w);
      s2.x = __builtin_fmaf(sc, dot8(wp +  64, xa, xb), s2.x);
      s2.y = __builtin_fmaf(sc, dot8(wp +  72, xa, xb), s2.y);
      s2.z = __builtin_fmaf(sc, dot8(wp +  80, xa, xb), s2.z);
      s2.w = __builtin_fmaf(sc, dot8(wp +  88, xa, xb), s2.w);
      s3.x = __builtin_fmaf(sc, dot8(wp +  96, xa, xb), s3.x);
      s3.y = __builtin_fmaf(sc, dot8(wp + 104, xa, xb), s3.y);
      s3.z = __builtin_fmaf(sc, dot8(wp + 112, xa, xb), s3.z);
      s3.w = __builtin_fmaf(sc, dot8(wp + 120, xa, xb), s3.w);
    }
    float* sp = s_out + (size_t)(o * P_) * B_ + lane;
    atomicAdd(&sp[ 0 * B_], s0.x); atomicAdd(&sp[ 1 * B_], s0.y);
    atomicAdd(&sp[ 2 * B_], s0.z); atomicAdd(&sp[ 3 * B_], s0.w);
    atomicAdd(&sp[ 4 * B_], s1.x); atomicAdd(&sp[ 5 * B_], s1.y);
    atomicAdd(&sp[ 6 * B_], s1.z); atomicAdd(&sp[ 7 * B_], s1.w);
    atomicAdd(&sp[ 8 * B_], s2.x); atomicAdd(&sp[ 9 * B_], s2.y);
    atomicAdd(&sp[10 * B_], s2.z); atomicAdd(&sp[11 * B_], s2.w);
    atomicAdd(&sp[12 * B_], s3.x); atomicAdd(&sp[13 * B_], s3.y);
    atomicAdd(&sp[14 * B_], s3.z); atomicAdd(&sp[15 * B_], s3.w);
  }
}

// squash s_buf (with scale), optionally add v_add; also zero next pass's s buffer.
__global__ __launch_bounds__(1024)
void v_kernel(const float* __restrict__ sbuf, float scale,
              const float* __restrict__ v_add, float* __restrict__ v_out,
              float* __restrict__ zero_buf) {
  __shared__ float sq[P_ * 64];
  const int t = threadIdx.x;
  const int b = t & 63;
  const int p = t >> 6;
  const int o = blockIdx.x;
  const int q = o * P_ + p;
  float acc = sbuf[q * 64 + b] * scale;
  sq[p * 64 + b] = acc * acc;
  if (zero_buf) zero_buf[blockIdx.x * 1024 + t] = 0.0f;   // 32*1024 == OP_*B_
  __syncthreads();
  float s2 = 0.0f;
  #pragma unroll
  for (int pp = 0; pp < P_; ++pp) s2 += sq[pp * 64 + b];
  float sc = (s2 / (1.0f + s2)) / sqrtf(s2 + 1e-7f);
  float v = acc * sc;
  const int idx = b * OP_ + q;   // v layout [b][o][p]
  v_out[idx] = v + (v_add ? v_add[idx] : 0.0f);
}

extern "C" void kernel_launch(void* const* d_in, const int* in_sizes, int n_in,
                              void* d_out, int out_size, void* d_ws, size_t ws_size,
                              hipStream_t stream) {
  (void)in_sizes; (void)n_in; (void)out_size; (void)ws_size;
  const float* x = (const float*)d_in[0];
  const float* W = (const float*)d_in[1];
  float* out_v  = (float*)d_out;                       // [64][32][16]
  float* out_rw = out_v + (size_t)B_ * O_ * P_;        // [64][2048][32]
  float* vws  = (float*)d_ws;                          // v0
  float* vsum = vws  + OP_ * B_;                       // v0+v1
  float* sA   = vsum + OP_ * B_;                       // s accumulators (ping)
  float* sB   = sA   + OP_ * B_;                       // (pong)

  dim3 gF(NBLK_), bF(1024), gV(O_), bV(1024);
  hipMemsetAsync(sA, 0, (size_t)OP_ * B_ * sizeof(float), stream);
  fused_pass<0><<<gF, bF, 0, stream>>>(x, W, nullptr, sA, nullptr);
  v_kernel<<<gV, bV, 0, stream>>>(sA, 1.0f / 32.0f, nullptr, vws, sB);
  fused_pass<1><<<gF, bF, 0, stream>>>(x, W, vws, sB, nullptr);
  v_kernel<<<gV, bV, 0, stream>>>(sB, 1.0f, vws, vsum, sA);
  fused_pass<2><<<gF, bF, 0, stream>>>(x, W, vsum, sA, out_rw);
  v_kernel<<<gV, bV, 0, stream>>>(sA, 1.0f, nullptr, out_v, nullptr);
}

// Round 4
// 287.426 us; speedup vs baseline: 1.5267x; 1.5267x over previous
//
#include <hip/hip_runtime.h>

static constexpr int B_    = 64;
static constexpr int N_    = 2048;
static constexpr int DI_   = 8;
static constexpr int O_    = 32;
static constexpr int P_    = 16;
static constexpr int OP_   = O_ * P_;      // 512
static constexpr int M_    = OP_ * B_;     // 32768 elements of s

__device__ __forceinline__ float dot8(const float* __restrict__ wp,
                                      const float4& xa, const float4& xb) {
  float pr = wp[0] * xa.x;
  pr = __builtin_fmaf(wp[1], xa.y, pr);
  pr = __builtin_fmaf(wp[2], xa.z, pr);
  pr = __builtin_fmaf(wp[3], xa.w, pr);
  pr = __builtin_fmaf(wp[4], xb.x, pr);
  pr = __builtin_fmaf(wp[5], xb.y, pr);
  pr = __builtin_fmaf(wp[6], xb.z, pr);
  pr = __builtin_fmaf(wp[7], xb.w, pr);
  return pr;
}

// MODE 0: iter0 (uniform rw; 1/32 folded into v_kernel scale). Phase B only.
// MODE 1: phase A (logits vs v_in) + softmax + phase B.
// MODE 2: MODE1 + write normalized rw to rw_out (v_in = v0+v1 by linearity).
// ATOMIC=false: block partial -> s_out[blk*M_ + ...]; true: atomicAdd (fallback).
template <int MODE, int CHUNK, bool ATOMIC>
__global__ __launch_bounds__(1024, 8)
void fused_pass(const float* __restrict__ x, const float* __restrict__ W,
                const float* __restrict__ v_in, float* __restrict__ s_out,
                float* __restrict__ rw_out) {
  __shared__ float x_lds[CHUNK * 8 * 65];     // [rem=(nn*8+i)][b], pad 65
  __shared__ float a_lds[CHUNK * O_ * B_];    // [nn][o][b] logits -> rw
  const int tid  = threadIdx.x;
  const int lane = tid & 63;                  // lane == batch b
  const int wave = tid >> 6;                  // 0..15
  const int n0   = blockIdx.x * CHUNK;

  // stage x[b][n0..n0+CHUNK-1][i] -> LDS
  #pragma unroll
  for (int k = 0; k < CHUNK / 2; ++k) {
    int d = k * 1024 + tid;
    int b = d / (CHUNK * 8), rem = d % (CHUNK * 8);
    x_lds[rem * 65 + b] = x[b * (N_ * DI_) + n0 * DI_ + rem];
  }
  __syncthreads();

  if (MODE != 0) {
    // ---- phase A: a[nn][o][b] = <preds(b,n,o,:), v(b,o,:)> ----
    #pragma unroll 1
    for (int oo = 0; oo < 2; ++oo) {
      const int o   = wave * 2 + oo;
      const int o_u = __builtin_amdgcn_readfirstlane(o);
      const float4* vp = (const float4*)(v_in + (size_t)lane * OP_ + o * P_);
      float4 v0 = vp[0], v1 = vp[1], v2 = vp[2], v3 = vp[3];
      #pragma unroll 2
      for (int nn = 0; nn < CHUNK; ++nn) {
        const float* wp = W + (size_t)((n0 + nn) * O_ + o_u) * (P_ * DI_);
        const float* xp = &x_lds[nn * 8 * 65 + lane];
        float4 xa, xb;
        xa.x = xp[0];   xa.y = xp[65];  xa.z = xp[130]; xa.w = xp[195];
        xb.x = xp[260]; xb.y = xp[325]; xb.z = xp[390]; xb.w = xp[455];
        float a;
        a = dot8(wp +   0, xa, xb) * v0.x;
        a = __builtin_fmaf(dot8(wp +   8, xa, xb), v0.y, a);
        a = __builtin_fmaf(dot8(wp +  16, xa, xb), v0.z, a);
        a = __builtin_fmaf(dot8(wp +  24, xa, xb), v0.w, a);
        a = __builtin_fmaf(dot8(wp +  32, xa, xb), v1.x, a);
        a = __builtin_fmaf(dot8(wp +  40, xa, xb), v1.y, a);
        a = __builtin_fmaf(dot8(wp +  48, xa, xb), v1.z, a);
        a = __builtin_fmaf(dot8(wp +  56, xa, xb), v1.w, a);
        a = __builtin_fmaf(dot8(wp +  64, xa, xb), v2.x, a);
        a = __builtin_fmaf(dot8(wp +  72, xa, xb), v2.y, a);
        a = __builtin_fmaf(dot8(wp +  80, xa, xb), v2.z, a);
        a = __builtin_fmaf(dot8(wp +  88, xa, xb), v2.w, a);
        a = __builtin_fmaf(dot8(wp +  96, xa, xb), v3.x, a);
        a = __builtin_fmaf(dot8(wp + 104, xa, xb), v3.y, a);
        a = __builtin_fmaf(dot8(wp + 112, xa, xb), v3.z, a);
        a = __builtin_fmaf(dot8(wp + 120, xa, xb), v3.w, a);
        a_lds[(nn * O_ + o) * B_ + lane] = a;
      }
    }
    __syncthreads();

    // ---- softmax over o (in-lane; wave nn handles its row) ----
    if (wave < CHUNK) {
      const int nn = wave;
      float* ap = &a_lds[nn * O_ * B_ + lane];
      float m = -3.0e38f;
      #pragma unroll
      for (int o = 0; o < O_; ++o) m = fmaxf(m, ap[o * B_]);
      float Z = 0.0f;
      #pragma unroll
      for (int o = 0; o < O_; ++o) Z += __expf(ap[o * B_] - m);
      float rZ = 1.0f / Z;
      if (MODE == 2) {
        float* rp = rw_out + ((size_t)lane * N_ + (n0 + nn)) * O_;
        #pragma unroll
        for (int o4 = 0; o4 < 8; ++o4) {
          float4 t;
          t.x = __expf(ap[(o4 * 4 + 0) * B_] - m) * rZ;
          t.y = __expf(ap[(o4 * 4 + 1) * B_] - m) * rZ;
          t.z = __expf(ap[(o4 * 4 + 2) * B_] - m) * rZ;
          t.w = __expf(ap[(o4 * 4 + 3) * B_] - m) * rZ;
          ap[(o4 * 4 + 0) * B_] = t.x;
          ap[(o4 * 4 + 1) * B_] = t.y;
          ap[(o4 * 4 + 2) * B_] = t.z;
          ap[(o4 * 4 + 3) * B_] = t.w;
          ((float4*)rp)[o4] = t;
        }
      } else {
        #pragma unroll
        for (int o = 0; o < O_; ++o) ap[o * B_] = __expf(ap[o * B_] - m) * rZ;
      }
    }
    __syncthreads();
  }

  // ---- phase B: s[b,o,p] += rw * preds (recompute preds) ----
  #pragma unroll 1
  for (int oo = 0; oo < 2; ++oo) {
    const int o   = wave * 2 + oo;
    const int o_u = __builtin_amdgcn_readfirstlane(o);
    float4 s0 = {0,0,0,0}, s1 = {0,0,0,0}, s2 = {0,0,0,0}, s3 = {0,0,0,0};
    #pragma unroll 2
    for (int nn = 0; nn < CHUNK; ++nn) {
      const float* wp = W + (size_t)((n0 + nn) * O_ + o_u) * (P_ * DI_);
      const float* xp = &x_lds[nn * 8 * 65 + lane];
      float4 xa, xb;
      xa.x = xp[0];   xa.y = xp[65];  xa.z = xp[130]; xa.w = xp[195];
      xb.x = xp[260]; xb.y = xp[325]; xb.z = xp[390]; xb.w = xp[455];
      const float sc = (MODE == 0) ? 1.0f : a_lds[(nn * O_ + o) * B_ + lane];
      s0.x = __builtin_fmaf(sc, dot8(wp +   0, xa, xb), s0.x);
      s0.y = __builtin_fmaf(sc, dot8(wp +   8, xa, xb), s0.y);
      s0.z = __builtin_fmaf(sc, dot8(wp +  16, xa, xb), s0.z);
      s0.w = __builtin_fmaf(sc, dot8(wp +  24, xa, xb), s0.w);
      s1.x = __builtin_fmaf(sc, dot8(wp +  32, xa, xb), s1.x);
      s1.y = __builtin_fmaf(sc, dot8(wp +  40, xa, xb), s1.y);
      s1.z = __builtin_fmaf(sc, dot8(wp +  48, xa, xb), s1.z);
      s1.w = __builtin_fmaf(sc, dot8(wp +  56, xa, xb), s1.w);
      s2.x = __builtin_fmaf(sc, dot8(wp +  64, xa, xb), s2.x);
      s2.y = __builtin_fmaf(sc, dot8(wp +  72, xa, xb), s2.y);
      s2.z = __builtin_fmaf(sc, dot8(wp +  80, xa, xb), s2.z);
      s2.w = __builtin_fmaf(sc, dot8(wp +  88, xa, xb), s2.w);
      s3.x = __builtin_fmaf(sc, dot8(wp +  96, xa, xb), s3.x);
      s3.y = __builtin_fmaf(sc, dot8(wp + 104, xa, xb), s3.y);
      s3.z = __builtin_fmaf(sc, dot8(wp + 112, xa, xb), s3.z);
      s3.w = __builtin_fmaf(sc, dot8(wp + 120, xa, xb), s3.w);
    }
    if (ATOMIC) {
      float* sp = s_out + (size_t)(o * P_) * B_ + lane;
      atomicAdd(&sp[ 0 * B_], s0.x); atomicAdd(&sp[ 1 * B_], s0.y);
      atomicAdd(&sp[ 2 * B_], s0.z); atomicAdd(&sp[ 3 * B_], s0.w);
      atomicAdd(&sp[ 4 * B_], s1.x); atomicAdd(&sp[ 5 * B_], s1.y);
      atomicAdd(&sp[ 6 * B_], s1.z); atomicAdd(&sp[ 7 * B_], s1.w);
      atomicAdd(&sp[ 8 * B_], s2.x); atomicAdd(&sp[ 9 * B_], s2.y);
      atomicAdd(&sp[10 * B_], s2.z); atomicAdd(&sp[11 * B_], s2.w);
      atomicAdd(&sp[12 * B_], s3.x); atomicAdd(&sp[13 * B_], s3.y);
      atomicAdd(&sp[14 * B_], s3.z); atomicAdd(&sp[15 * B_], s3.w);
    } else {
      float* sp = s_out + (size_t)blockIdx.x * M_ + (size_t)(o * P_) * B_ + lane;
      sp[ 0 * B_] = s0.x; sp[ 1 * B_] = s0.y; sp[ 2 * B_] = s0.z; sp[ 3 * B_] = s0.w;
      sp[ 4 * B_] = s1.x; sp[ 5 * B_] = s1.y; sp[ 6 * B_] = s1.z; sp[ 7 * B_] = s1.w;
      sp[ 8 * B_] = s2.x; sp[ 9 * B_] = s2.y; sp[10 * B_] = s2.z; sp[11 * B_] = s2.w;
      sp[12 * B_] = s3.x; sp[13 * B_] = s3.y; sp[14 * B_] = s3.z; sp[15 * B_] = s3.w;
    }
  }
}

// stage-1 reduction: P[K][M_] -> P2[16][M_]; grid 16 groups x 16 m-chunks, 1024 thr.
__global__ __launch_bounds__(1024)
void reduce1(const float* __restrict__ spart, float* __restrict__ p2, int K) {
  const int g  = blockIdx.x >> 4;
  const int mc = blockIdx.x & 15;
  const int kpg = K >> 4;
  const int m0 = mc * 2048 + threadIdx.x;
  float a0 = 0.0f, a1 = 0.0f;
  const float* p = spart + (size_t)(g * kpg) * M_;
  for (int k = 0; k < kpg; ++k) {
    a0 += p[(size_t)k * M_ + m0];
    a1 += p[(size_t)k * M_ + m0 + 1024];
  }
  p2[(size_t)g * M_ + m0]        = a0;
  p2[(size_t)g * M_ + m0 + 1024] = a1;
}

// sum ngroups (stride M_) + squash; optionally add v_add; optionally zero a buffer.
__global__ __launch_bounds__(1024)
void v_kernel(const float* __restrict__ src, int ngroups, float scale,
              const float* __restrict__ v_add, float* __restrict__ v_out,
              float* __restrict__ zero_buf) {
  __shared__ float sq[P_ * 64];
  const int t = threadIdx.x;
  const int b = t & 63;
  const int p = t >> 6;
  const int o = blockIdx.x;
  const int q = o * P_ + p;
  float acc = 0.0f;
  for (int g = 0; g < ngroups; ++g) acc += src[(size_t)g * M_ + q * 64 + b];
  acc *= scale;
  sq[p * 64 + b] = acc * acc;
  if (zero_buf) zero_buf[blockIdx.x * 1024 + t] = 0.0f;   // 32*1024 == M_
  __syncthreads();
  float s2 = 0.0f;
  #pragma unroll
  for (int pp = 0; pp < P_; ++pp) s2 += sq[pp * 64 + b];
  float sc = (s2 / (1.0f + s2)) / sqrtf(s2 + 1e-7f);
  float v = acc * sc;
  const int idx = b * OP_ + q;   // v layout [b][o][p]
  v_out[idx] = v + (v_add ? v_add[idx] : 0.0f);
}

extern "C" void kernel_launch(void* const* d_in, const int* in_sizes, int n_in,
                              void* d_out, int out_size, void* d_ws, size_t ws_size,
                              hipStream_t stream) {
  (void)in_sizes; (void)n_in; (void)out_size;
  const float* x = (const float*)d_in[0];
  const float* W = (const float*)d_in[1];
  float* out_v  = (float*)d_out;                       // [64][32][16]
  float* out_rw = out_v + (size_t)B_ * O_ * P_;        // [64][2048][32]
  float* vws   = (float*)d_ws;                         // v0
  float* vsum  = vws  + M_ / 64;                       // (M_/64 == OP_*B_/64? no)
  // NOTE: vws/vsum are OP_*B_ = M_ floats?  v is only B_*OP_ = 32768 floats = M_.
  vsum = vws + M_;
  float* p2    = vsum + M_;                            // 16 * M_ floats
  float* spart = p2 + 16 * M_;

  const size_t need512 = (size_t)(2 * M_ + 16 * M_ + 512 * M_) * 4;
  const size_t need256 = (size_t)(2 * M_ + 16 * M_ + 256 * M_) * 4;

  dim3 bF(1024), gV(O_), bV(1024), gR(256);
  if (ws_size >= need512) {
    dim3 gF(512);
    fused_pass<0, 4, false><<<gF, bF, 0, stream>>>(x, W, nullptr, spart, nullptr);
    reduce1<<<gR, bF, 0, stream>>>(spart, p2, 512);
    v_kernel<<<gV, bV, 0, stream>>>(p2, 16, 1.0f / 32.0f, nullptr, vws, nullptr);
    fused_pass<1, 4, false><<<gF, bF, 0, stream>>>(x, W, vws, spart, nullptr);
    reduce1<<<gR, bF, 0, stream>>>(spart, p2, 512);
    v_kernel<<<gV, bV, 0, stream>>>(p2, 16, 1.0f, vws, vsum, nullptr);
    fused_pass<2, 4, false><<<gF, bF, 0, stream>>>(x, W, vsum, spart, out_rw);
    reduce1<<<gR, bF, 0, stream>>>(spart, p2, 512);
    v_kernel<<<gV, bV, 0, stream>>>(p2, 16, 1.0f, nullptr, out_v, nullptr);
  } else if (ws_size >= need256) {
    dim3 gF(256);
    fused_pass<0, 8, false><<<gF, bF, 0, stream>>>(x, W, nullptr, spart, nullptr);
    reduce1<<<gR, bF, 0, stream>>>(spart, p2, 256);
    v_kernel<<<gV, bV, 0, stream>>>(p2, 16, 1.0f / 32.0f, nullptr, vws, nullptr);
    fused_pass<1, 8, false><<<gF, bF, 0, stream>>>(x, W, vws, spart, nullptr);
    reduce1<<<gR, bF, 0, stream>>>(spart, p2, 256);
    v_kernel<<<gV, bV, 0, stream>>>(p2, 16, 1.0f, vws, vsum, nullptr);
    fused_pass<2, 8, false><<<gF, bF, 0, stream>>>(x, W, vsum, spart, out_rw);
    reduce1<<<gR, bF, 0, stream>>>(spart, p2, 256);
    v_kernel<<<gV, bV, 0, stream>>>(p2, 16, 1.0f, nullptr, out_v, nullptr);
  } else {
    // atomic fallback (slow but tiny ws): sA = p2 slot, sB after it
    float* sA = p2;
    float* sB = sA + M_;
    dim3 gF(512);
    hipMemsetAsync(sA, 0, (size_t)M_ * sizeof(float), stream);
    fused_pass<0, 4, true><<<gF, bF, 0, stream>>>(x, W, nullptr, sA, nullptr);
    v_kernel<<<gV, bV, 0, stream>>>(sA, 1, 1.0f / 32.0f, nullptr, vws, sB);
    fused_pass<1, 4, true><<<gF, bF, 0, stream>>>(x, W, vws, sB, nullptr);
    v_kernel<<<gV, bV, 0, stream>>>(sB, 1, 1.0f, vws, vsum, sA);
    fused_pass<2, 4, true><<<gF, bF, 0, stream>>>(x, W, vsum, sA, out_rw);
    v_kernel<<<gV, bV, 0, stream>>>(sA, 1, 1.0f, nullptr, out_v, nullptr);
  }
}